// Round 1
// baseline (99435.162 us; speedup 1.0000x reference)
//
#include <hip/hip_runtime.h>
#include <math.h>

namespace {

constexpr int B_ = 128;
constexpr int T_ = 500;
constexpr int F_ = 64;
constexpr int U_ = 512;
constexpr int NCLS_ = 11;
constexpr int FOURU = 4 * U_;        // 2048
constexpr float R_ON_ = 0.05f;
constexpr float ALPHA_ = 0.001f;

constexpr int GRID_BLOCKS = 528;     // 256 cell0 + 256 cell1 + 16 classifier
constexpr int BLOCK_THREADS = 256;
constexpr int HU = B_ * U_;          // 65536 floats per state buffer

__device__ __forceinline__ float sigmoidf_(float x) {
  return 1.0f / (1.0f + expf(-x));
}

// Sense-reversing device-wide barrier. cnt and gen on separate cache lines so
// spinners polling gen don't contend with the arrival RMWs on cnt.
__device__ __forceinline__ void grid_barrier(unsigned* cnt, unsigned* gen) {
  __syncthreads();
  if (threadIdx.x == 0) {
    __threadfence();  // make this block's global writes visible device-wide
    unsigned g = __hip_atomic_load(gen, __ATOMIC_RELAXED, __HIP_MEMORY_SCOPE_AGENT);
    unsigned a = __hip_atomic_fetch_add(cnt, 1u, __ATOMIC_ACQ_REL, __HIP_MEMORY_SCOPE_AGENT);
    if (a == (unsigned)(GRID_BLOCKS - 1)) {
      __hip_atomic_store(cnt, 0u, __ATOMIC_RELAXED, __HIP_MEMORY_SCOPE_AGENT);
      __hip_atomic_store(gen, g + 1u, __ATOMIC_RELEASE, __HIP_MEMORY_SCOPE_AGENT);
    } else {
      while (__hip_atomic_load(gen, __ATOMIC_ACQUIRE, __HIP_MEMORY_SCOPE_AGENT) == g) {
        __builtin_amdgcn_s_sleep(1);
      }
    }
  }
  __syncthreads();
}

// One PhasedLSTM cell step for this block's tile:
//   rows [r0, r0+16), units [u0, u0+16)  -> z-tile 16 x 64 (4 gates x 16 u)
// A = [A1 (K1 wide) | A2 (U_ wide)],  W = [W1 ; W2]  (both [K][2048])
__device__ void cell_step(
    const float* __restrict__ A1, int ldA1, int K1,
    const float* __restrict__ A2,
    const float* __restrict__ W1, const float* __restrict__ W2,
    const float* __restrict__ bias,
    const float* __restrict__ tau, const float* __restrict__ shift,
    const float* __restrict__ times_t,   // == times + t ; element [b*T_]
    float* __restrict__ cbuf,
    const float* __restrict__ hprev,
    float* __restrict__ hout,
    int r0, int u0, float* lds)
{
  float* a_s = lds;                       // [32][18]  (16 rows + 2 pad)
  float* w_s = lds + 32 * 18;             // [32][64]
  float* z_s = lds + 32 * 18 + 32 * 64;   // [16][64]

  const int tid = threadIdx.x;
  const int col_t = tid & 31;             // 2 cols each
  const int row_t = tid >> 5;             // 2 rows each
  const int srow = tid >> 4;              // A staging: row 0..15
  const int sk = (tid & 15) << 1;         // A staging: k pair
  const int wk = tid >> 3;                // W staging: k row 0..31
  const int wc = (tid & 7) << 3;          // W staging: tile col base (8 cols)
  const int wcol = ((wc >> 4) << 9) + u0 + (wc & 15);  // global W column

  float acc00 = 0.f, acc01 = 0.f, acc10 = 0.f, acc11 = 0.f;

  const int K = K1 + U_;
  for (int kb = 0; kb < K; kb += 32) {
    const float* Ap; int lda; int ak; const float* Wp;
    if (kb < K1) { Ap = A1; lda = ldA1; ak = kb;      Wp = W1 + (size_t)kb * FOURU; }
    else         { Ap = A2; lda = U_;   ak = kb - K1; Wp = W2 + (size_t)(kb - K1) * FOURU; }

    const float2 av  = *(const float2*)(Ap + (size_t)(r0 + srow) * lda + ak + sk);
    const float4 wv0 = *(const float4*)(Wp + (size_t)wk * FOURU + wcol);
    const float4 wv1 = *(const float4*)(Wp + (size_t)wk * FOURU + wcol + 4);

    __syncthreads();   // previous chunk's LDS reads complete
    a_s[sk * 18 + srow]       = av.x;
    a_s[(sk + 1) * 18 + srow] = av.y;
    *(float4*)(w_s + wk * 64 + wc)     = wv0;
    *(float4*)(w_s + wk * 64 + wc + 4) = wv1;
    __syncthreads();

#pragma unroll
    for (int kk = 0; kk < 32; ++kk) {
      const float2 a = *(const float2*)(a_s + kk * 18 + (row_t << 1));
      const float2 w = *(const float2*)(w_s + kk * 64 + (col_t << 1));
      acc00 = fmaf(a.x, w.x, acc00);
      acc01 = fmaf(a.x, w.y, acc01);
      acc10 = fmaf(a.y, w.x, acc10);
      acc11 = fmaf(a.y, w.y, acc11);
    }
  }

  // exchange z through LDS so each thread gets all 4 gates of one (b,u)
  *(float2*)(z_s + ((row_t << 1) + 0) * 64 + (col_t << 1)) = make_float2(acc00, acc01);
  *(float2*)(z_s + ((row_t << 1) + 1) * 64 + (col_t << 1)) = make_float2(acc10, acc11);
  __syncthreads();

  const int erow = tid >> 4;
  const int eu = tid & 15;
  const int b = r0 + erow;
  const int u = u0 + eu;

  const float zi = z_s[erow * 64 +      eu] + bias[u];
  const float zf = z_s[erow * 64 + 16 + eu] + bias[U_ + u];
  const float zg = z_s[erow * 64 + 32 + eu] + bias[2 * U_ + u];
  const float zo = z_s[erow * 64 + 48 + eu] + bias[3 * U_ + u];

  const float ig = sigmoidf_(zi);
  const float fg = sigmoidf_(zf);
  const float gg = tanhf(zg);
  const float og = sigmoidf_(zo);

  const int su = b * U_ + u;
  const float c_old = cbuf[su];
  const float c_t = fg * c_old + ig * gg;
  const float h_t = og * tanhf(c_t);

  const float tt = times_t[(size_t)b * T_];
  const float tau_u = tau[u];
  float phi = fmodf(tt - shift[u], tau_u);
  if (phi < 0.f) phi += tau_u;
  phi /= tau_u;
  float kt;
  if (phi < 0.5f * R_ON_)      kt = phi * (2.0f / R_ON_);
  else if (phi < R_ON_)        kt = 2.0f - phi * (2.0f / R_ON_);
  else                         kt = ALPHA_ * phi;

  const float h_old = hprev[su];
  cbuf[su] = kt * c_t + (1.0f - kt) * c_old;
  hout[su] = kt * h_t + (1.0f - kt) * h_old;
}

// 16 classifier blocks, 8 batch-rows each: logits = h1[b] @ wfc + bfc, softmax.
__device__ void classifier_step(int cb, int t,
    const float* __restrict__ h1s,
    const float* __restrict__ wfc, const float* __restrict__ bfc,
    float* __restrict__ out)
{
  const int tid = threadIdx.x;
  const int bl = tid >> 5;               // 0..7
  const int lane = tid & 31;
  const int b = cb * 8 + bl;
  const float* hrow = h1s + (size_t)b * U_;

  float acc[NCLS_];
#pragma unroll
  for (int c = 0; c < NCLS_; ++c) acc[c] = 0.f;

  for (int j = 0; j < U_ / 32; ++j) {
    const float h = hrow[lane + 32 * j];
    const float* w = wfc + (size_t)(lane + 32 * j) * NCLS_;
#pragma unroll
    for (int c = 0; c < NCLS_; ++c) acc[c] = fmaf(h, w[c], acc[c]);
  }
#pragma unroll
  for (int off = 16; off >= 1; off >>= 1) {
#pragma unroll
    for (int c = 0; c < NCLS_; ++c) acc[c] += __shfl_xor(acc[c], off, 64);
  }
  if (lane == 0) {
    float lg[NCLS_];
    float m = -1e30f;
#pragma unroll
    for (int c = 0; c < NCLS_; ++c) { lg[c] = acc[c] + bfc[c]; m = fmaxf(m, lg[c]); }
    float s = 0.f;
#pragma unroll
    for (int c = 0; c < NCLS_; ++c) { lg[c] = expf(lg[c] - m); s += lg[c]; }
    const float inv = 1.0f / s;
    float* op = out + ((size_t)b * T_ + t) * NCLS_;
#pragma unroll
    for (int c = 0; c < NCLS_; ++c) op[c] = lg[c] * inv;
  }
}

__global__ void init_kernel(float* h0buf, float* c0buf, float* h1buf, float* c1buf,
                            unsigned* bar) {
  const size_t i = (size_t)blockIdx.x * blockDim.x + threadIdx.x;
  if (i < (size_t)HU) {
    h0buf[i] = 0.f; c0buf[i] = 0.f; h1buf[i] = 0.f; c1buf[i] = 0.f;
  }
  if (i == 0) { bar[0] = 0u; bar[16] = 0u; }
}

// Persistent kernel. Phase ph computes:
//   cell0 for t = ph        (blocks 0..255)     [needs h0(ph-1)]
//   cell1 for t = ph-1      (blocks 256..511)   [needs h0(ph-1) ... i.e. h0 of its t]
//   classifier for t = ph-2 (blocks 512..527)   [needs h1(ph-2)]
// -> exactly one grid barrier per phase, T+1 barriers total.
__global__ __launch_bounds__(BLOCK_THREADS, 4) void plstm_kernel(
    const float* __restrict__ inputs, const float* __restrict__ times,
    const float* __restrict__ k0, const float* __restrict__ rk0,
    const float* __restrict__ b0, const float* __restrict__ tau0, const float* __restrict__ s0,
    const float* __restrict__ k1, const float* __restrict__ rk1,
    const float* __restrict__ b1, const float* __restrict__ tau1, const float* __restrict__ s1,
    const float* __restrict__ wfc, const float* __restrict__ bfc,
    float* __restrict__ out,
    float* __restrict__ h0buf, float* __restrict__ c0buf,
    float* __restrict__ h1buf, float* __restrict__ c1buf,
    unsigned* __restrict__ bar)
{
  __shared__ float lds[32 * 18 + 32 * 64 + 16 * 64];
  const int bid = blockIdx.x;

  for (int ph = 0; ph <= T_ + 1; ++ph) {
    if (bid < 256) {
      const int t = ph;
      if (t < T_) {
        const int r0 = (bid >> 5) << 4;
        const int u0 = (bid & 31) << 4;
        const float* h0in = h0buf + (size_t)(t & 1) * HU;
        float* h0out      = h0buf + (size_t)((t + 1) & 1) * HU;
        cell_step(inputs + (size_t)t * F_, T_ * F_, F_,
                  h0in, k0, rk0, b0, tau0, s0,
                  times + t, c0buf, h0in, h0out, r0, u0, lds);
      }
    } else if (bid < 512) {
      const int t = ph - 1;
      if (t >= 0 && t < T_) {
        const int b2 = bid - 256;
        const int r0 = (b2 >> 5) << 4;
        const int u0 = (b2 & 31) << 4;
        const float* h0st = h0buf + (size_t)((t + 1) & 1) * HU;  // h0 state at time t
        const float* h1in = h1buf + (size_t)(t & 1) * HU;
        float* h1out      = h1buf + (size_t)((t + 1) & 1) * HU;
        cell_step(h0st, U_, U_,
                  h1in, k1, rk1, b1, tau1, s1,
                  times + t, c1buf, h1in, h1out, r0, u0, lds);
      }
    } else {
      const int t = ph - 2;
      if (t >= 0) {
        classifier_step(bid - 512, t, h1buf + (size_t)((t + 1) & 1) * HU, wfc, bfc, out);
      }
    }
    if (ph <= T_) grid_barrier(bar, bar + 16);
  }
}

}  // namespace

extern "C" void kernel_launch(void* const* d_in, const int* in_sizes, int n_in,
                              void* d_out, int out_size, void* d_ws, size_t ws_size,
                              hipStream_t stream) {
  const float* inputs = (const float*)d_in[0];
  const float* times  = (const float*)d_in[1];
  const float* k0     = (const float*)d_in[2];
  const float* rk0    = (const float*)d_in[3];
  const float* b0     = (const float*)d_in[4];
  const float* tau0   = (const float*)d_in[5];
  const float* s0     = (const float*)d_in[6];
  const float* k1     = (const float*)d_in[7];
  const float* rk1    = (const float*)d_in[8];
  const float* b1     = (const float*)d_in[9];
  const float* tau1   = (const float*)d_in[10];
  const float* s1     = (const float*)d_in[11];
  const float* wfc    = (const float*)d_in[12];
  const float* bfc    = (const float*)d_in[13];
  float* out = (float*)d_out;

  float* ws = (float*)d_ws;
  float* h0buf = ws;                 // [2][B][U]
  float* c0buf = ws + 2 * HU;        // [B][U]
  float* h1buf = ws + 3 * HU;        // [2][B][U]
  float* c1buf = ws + 5 * HU;        // [B][U]
  unsigned* bar = (unsigned*)(ws + 6 * HU);  // bar[0]=cnt, bar[16]=gen

  hipLaunchKernelGGL(init_kernel, dim3(256), dim3(256), 0, stream,
                     h0buf, c0buf, h1buf, c1buf, bar);
  hipLaunchKernelGGL(plstm_kernel, dim3(GRID_BLOCKS), dim3(BLOCK_THREADS), 0, stream,
                     inputs, times, k0, rk0, b0, tau0, s0,
                     k1, rk1, b1, tau1, s1, wfc, bfc,
                     out, h0buf, c0buf, h1buf, c1buf, bar);
}

// Round 2
// 41674.667 us; speedup vs baseline: 2.3860x; 2.3860x over previous
//
#include <hip/hip_runtime.h>
#include <math.h>

namespace {

typedef __attribute__((ext_vector_type(8))) short s8b;   // 8 x bf16 (bit pattern)
typedef __attribute__((ext_vector_type(4))) float f4;

constexpr int B_ = 128;
constexpr int T_ = 500;
constexpr int F_ = 64;
constexpr int U_ = 512;
constexpr int NCLS_ = 11;
constexpr int HU = B_ * U_;           // 65536
constexpr float R_ON_ = 0.05f;
constexpr float ALPHA_ = 0.001f;

constexpr int GRID_BLOCKS = 144;      // 64 cell0 + 64 cell1 + 16 classifier
constexpr int NPH = 502;              // phases 0..501

__device__ __forceinline__ ushort bf16_rne(float f) {
  union { float f; unsigned u; } v; v.f = f;
  unsigned r = (v.u + 0x7fffu + ((v.u >> 16) & 1u)) >> 16;
  return (ushort)r;
}
__device__ __forceinline__ float bf16_f(ushort h) {
  union { unsigned u; float f; } v; v.u = ((unsigned)h) << 16; return v.f;
}

__device__ __forceinline__ void grid_barrier(unsigned* cnt, unsigned* gen) {
  __syncthreads();
  if (threadIdx.x == 0) {
    __threadfence();
    unsigned g = __hip_atomic_load(gen, __ATOMIC_RELAXED, __HIP_MEMORY_SCOPE_AGENT);
    unsigned a = __hip_atomic_fetch_add(cnt, 1u, __ATOMIC_ACQ_REL, __HIP_MEMORY_SCOPE_AGENT);
    if (a == (unsigned)(GRID_BLOCKS - 1)) {
      __hip_atomic_store(cnt, 0u, __ATOMIC_RELAXED, __HIP_MEMORY_SCOPE_AGENT);
      __hip_atomic_store(gen, g + 1u, __ATOMIC_RELEASE, __HIP_MEMORY_SCOPE_AGENT);
    } else {
      while (__hip_atomic_load(gen, __ATOMIC_ACQUIRE, __HIP_MEMORY_SCOPE_AGENT) == g) {
        __builtin_amdgcn_s_sleep(1);
      }
    }
  }
  __syncthreads();
}

// Load this wave's persistent weight fragments (hi/lo bf16 split) from the
// fp32 weights. W = [W1 (K1 rows); W2], column n. One-time cost.
template <int NKS>
__device__ __forceinline__ void load_weights(
    s8b (&wh)[NKS], s8b (&wl)[NKS],
    const float* __restrict__ W1, int K1, const float* __restrict__ W2,
    int n, int kbase, int krow)
{
#pragma unroll
  for (int ks = 0; ks < NKS; ++ks) {
#pragma unroll
    for (int j = 0; j < 8; ++j) {
      const int kg = kbase + ks * 32 + krow + j;
      const float* src = (kg < K1) ? (W1 + (size_t)kg * 2048)
                                   : (W2 + (size_t)(kg - K1) * 2048);
      const float wv = src[n];
      const ushort hi = bf16_rne(wv);
      const ushort lo = bf16_rne(wv - bf16_f(hi));
      wh[ks][j] = (short)hi;
      wl[ks][j] = (short)lo;
    }
  }
}

// One wave's GEMM slice for this phase: 16 cols (its coltile) x 128 rows x
// its K-slice, 3-term bf16-split MFMA. accs[rt] = partial z for rowtile rt.
template <int NKS, bool C0>
__device__ __forceinline__ void gemm_phase(
    const s8b (&wh)[NKS], const s8b (&wl)[NKS],
    int t, int ksl, int lane,
    const float* __restrict__ inputs,
    const ushort* __restrict__ Ahi, const ushort* __restrict__ Alo,
    int lkbase, f4 (&accs)[8])
{
  const int arow = lane & 15;
  const int krow = (lane >> 4) * 8;
#pragma unroll
  for (int rt = 0; rt < 8; ++rt) {
    const int row = rt * 16 + arow;
    f4 a0 = {0.f, 0.f, 0.f, 0.f};
    f4 a1 = {0.f, 0.f, 0.f, 0.f};
    f4 a2 = {0.f, 0.f, 0.f, 0.f};
#pragma unroll
    for (int ks = 0; ks < NKS; ++ks) {
      s8b ah, al;
      if (C0 && ksl == 0 && ks < 2) {
        // A-source = x[t] (fp32, split on the fly)
        const float* xp = inputs + ((size_t)row * T_ + t) * F_ + ks * 32 + krow;
        const float4 v0 = *(const float4*)xp;
        const float4 v1 = *(const float4*)(xp + 4);
        const float xv[8] = {v0.x, v0.y, v0.z, v0.w, v1.x, v1.y, v1.z, v1.w};
#pragma unroll
        for (int j = 0; j < 8; ++j) {
          const ushort hi = bf16_rne(xv[j]);
          ah[j] = (short)hi;
          al[j] = (short)bf16_rne(xv[j] - bf16_f(hi));
        }
      } else {
        const int lk = lkbase + ks * 32 + krow;
        ah = *(const s8b*)(Ahi + (size_t)row * U_ + lk);
        al = *(const s8b*)(Alo + (size_t)row * U_ + lk);
      }
      a0 = __builtin_amdgcn_mfma_f32_16x16x32_bf16(ah, wh[ks], a0, 0, 0, 0);
      a1 = __builtin_amdgcn_mfma_f32_16x16x32_bf16(al, wh[ks], a1, 0, 0, 0);
      a2 = __builtin_amdgcn_mfma_f32_16x16x32_bf16(ah, wl[ks], a2, 0, 0, 0);
    }
    accs[rt] = a0 + a1 + a2;
  }
}

// K-reduce the two K-slice waves through LDS, then the fused PhasedLSTM
// elementwise update for this block's 8 units x 128 batch rows.
__device__ __forceinline__ void reduce_elem(
    f4 (&accs)[8], float* __restrict__ z_s,
    int tid, int lane, int ksl, int c_loc,
    int t, int u0,
    const float* __restrict__ bias, const float* __restrict__ tau,
    const float* __restrict__ shift, const float* __restrict__ times,
    const float* __restrict__ hf_r, float* __restrict__ hf_w,
    ushort* __restrict__ hhi_w, ushort* __restrict__ hlo_w,
    float* __restrict__ cbuf)
{
  const int rbase = (lane >> 4) * 4;
  if (ksl == 0) {
#pragma unroll
    for (int rt = 0; rt < 8; ++rt)
      *(f4*)&z_s[c_loc * 132 + rt * 16 + rbase] = accs[rt];
  }
  __syncthreads();
  if (ksl == 1) {
#pragma unroll
    for (int rt = 0; rt < 8; ++rt) {
      f4* p = (f4*)&z_s[c_loc * 132 + rt * 16 + rbase];
      *p = *p + accs[rt];
    }
  }
  __syncthreads();

  const int b = tid & 127;
  const int up = tid >> 7;   // 0 or 1
#pragma unroll
  for (int i = 0; i < 4; ++i) {
    const int uu = i * 2 + up;
    const int u = u0 + uu;
    const float zi = z_s[(4 * uu + 0) * 132 + b] + bias[u];
    const float zf = z_s[(4 * uu + 1) * 132 + b] + bias[512 + u];
    const float zg = z_s[(4 * uu + 2) * 132 + b] + bias[1024 + u];
    const float zo = z_s[(4 * uu + 3) * 132 + b] + bias[1536 + u];

    const float ig = 1.f / (1.f + expf(-zi));
    const float fg = 1.f / (1.f + expf(-zf));
    const float gg = tanhf(zg);
    const float og = 1.f / (1.f + expf(-zo));

    const size_t su = (size_t)b * U_ + u;
    const float c_old = cbuf[su];
    const float c_t = fg * c_old + ig * gg;
    const float h_t = og * tanhf(c_t);

    const float tt = times[(size_t)b * T_ + t];
    const float tau_u = tau[u];
    float phi = fmodf(tt - shift[u], tau_u);
    if (phi < 0.f) phi += tau_u;
    phi /= tau_u;
    float kt;
    if (phi < 0.5f * R_ON_)      kt = phi * (2.0f / R_ON_);
    else if (phi < R_ON_)        kt = 2.0f - phi * (2.0f / R_ON_);
    else                         kt = ALPHA_ * phi;

    const float h_old = hf_r[su];
    const float cn = kt * c_t + (1.0f - kt) * c_old;
    const float hn = kt * h_t + (1.0f - kt) * h_old;
    cbuf[su] = cn;
    hf_w[su] = hn;
    const ushort hi = bf16_rne(hn);
    hhi_w[su] = hi;
    hlo_w[su] = bf16_rne(hn - bf16_f(hi));
  }
}

__device__ void classifier_step(int cb, int t,
    const float* __restrict__ h1s,
    const float* __restrict__ wfc, const float* __restrict__ bfc,
    float* __restrict__ out)
{
  const int tid = threadIdx.x;
  const int bl = tid >> 5;
  const int lane = tid & 31;
  const int b = cb * 8 + bl;
  const float* hrow = h1s + (size_t)b * U_;

  float acc[NCLS_];
#pragma unroll
  for (int c = 0; c < NCLS_; ++c) acc[c] = 0.f;
  for (int j = 0; j < U_ / 32; ++j) {
    const float h = hrow[lane + 32 * j];
    const float* w = wfc + (size_t)(lane + 32 * j) * NCLS_;
#pragma unroll
    for (int c = 0; c < NCLS_; ++c) acc[c] = fmaf(h, w[c], acc[c]);
  }
#pragma unroll
  for (int off = 16; off >= 1; off >>= 1) {
#pragma unroll
    for (int c = 0; c < NCLS_; ++c) acc[c] += __shfl_xor(acc[c], off, 64);
  }
  if (lane == 0) {
    float lg[NCLS_];
    float m = -1e30f;
#pragma unroll
    for (int c = 0; c < NCLS_; ++c) { lg[c] = acc[c] + bfc[c]; m = fmaxf(m, lg[c]); }
    float s = 0.f;
#pragma unroll
    for (int c = 0; c < NCLS_; ++c) { lg[c] = expf(lg[c] - m); s += lg[c]; }
    const float inv = 1.0f / s;
    float* op = out + ((size_t)b * T_ + t) * NCLS_;
#pragma unroll
    for (int c = 0; c < NCLS_; ++c) op[c] = lg[c] * inv;
  }
}

__global__ void init_kernel(float* ws0, unsigned* bar) {
  const size_t i = (size_t)blockIdx.x * blockDim.x + threadIdx.x;
  if (i < (size_t)10 * HU) ws0[i] = 0.f;
  if (i == 0) { bar[0] = 0u; bar[16] = 0u; }
}

// Phase ph: cell0 computes t=ph (blocks 0..63), cell1 t=ph-1 (blocks 64..127),
// classifier t=ph-2 (blocks 128..143). One grid barrier per phase.
__global__ __launch_bounds__(256, 1) void plstm_kernel(
    const float* __restrict__ inputs, const float* __restrict__ times,
    const float* __restrict__ k0, const float* __restrict__ rk0,
    const float* __restrict__ b0, const float* __restrict__ tau0, const float* __restrict__ s0,
    const float* __restrict__ k1, const float* __restrict__ rk1,
    const float* __restrict__ b1, const float* __restrict__ tau1, const float* __restrict__ s1,
    const float* __restrict__ wfc, const float* __restrict__ bfc,
    float* __restrict__ out,
    float* __restrict__ h0f, float* __restrict__ h1f,
    float* __restrict__ c0, float* __restrict__ c1,
    ushort* __restrict__ h0hi, ushort* __restrict__ h0lo,
    ushort* __restrict__ h1hi, ushort* __restrict__ h1lo,
    unsigned* __restrict__ bar)
{
  __shared__ __align__(16) float z_s[32 * 132];
  const int bid = blockIdx.x;
  const int tid = threadIdx.x;
  const int w = tid >> 6;
  const int lane = tid & 63;
  const int ct = w & 1;
  const int ksl = w >> 1;
  const int c_loc = ct * 16 + (lane & 15);
  const int krow = (lane >> 4) * 8;

  if (bid < 64) {
    // ---- cell 0: K = 576 (64 x + 512 h0), two K-slices of 288 ----
    const int u0 = bid * 8;
    const int n = (c_loc & 3) * 512 + u0 + (c_loc >> 2);
    s8b wh[9], wl[9];
    load_weights<9>(wh, wl, k0, 64, rk0, n, ksl * 288, krow);

    for (int ph = 0; ph < NPH; ++ph) {
      const int t = ph;
      if (t < T_) {
        const size_t rp = (size_t)(ph & 1) * HU;        // read parity
        const size_t wp = (size_t)((ph + 1) & 1) * HU;  // write parity
        f4 accs[8];
        gemm_phase<9, true>(wh, wl, t, ksl, lane, inputs,
                            h0hi + rp, h0lo + rp, ksl * 288 - 64, accs);
        reduce_elem(accs, z_s, tid, lane, ksl, c_loc, t, u0,
                    b0, tau0, s0, times,
                    h0f + rp, h0f + wp, h0hi + wp, h0lo + wp, c0);
      }
      if (ph < NPH - 1) grid_barrier(bar, bar + 16);
    }
  } else if (bid < 128) {
    // ---- cell 1: K = 1024 (512 h0new + 512 h1old), two K-slices of 512 ----
    const int u0 = (bid - 64) * 8;
    const int n = (c_loc & 3) * 512 + u0 + (c_loc >> 2);
    s8b wh[16], wl[16];
    load_weights<16>(wh, wl, k1, 512, rk1, n, ksl * 512, krow);

    for (int ph = 0; ph < NPH; ++ph) {
      const int t = ph - 1;
      if (t >= 0 && t < T_) {
        const size_t p_h0 = (size_t)(ph & 1) * HU;        // h0(t) just written
        const size_t p_h1r = (size_t)((ph + 1) & 1) * HU; // h1(t-1)
        const size_t p_h1w = (size_t)(ph & 1) * HU;       // h1(t)
        const ushort* Ahi = ksl ? (h1hi + p_h1r) : (h0hi + p_h0);
        const ushort* Alo = ksl ? (h1lo + p_h1r) : (h0lo + p_h0);
        f4 accs[8];
        gemm_phase<16, false>(wh, wl, t, ksl, lane, inputs, Ahi, Alo, 0, accs);
        reduce_elem(accs, z_s, tid, lane, ksl, c_loc, t, u0,
                    b1, tau1, s1, times,
                    h1f + p_h1r, h1f + p_h1w, h1hi + p_h1w, h1lo + p_h1w, c1);
      }
      if (ph < NPH - 1) grid_barrier(bar, bar + 16);
    }
  } else {
    // ---- classifier ----
    for (int ph = 0; ph < NPH; ++ph) {
      const int t = ph - 2;
      if (t >= 0 && t < T_) {
        classifier_step(bid - 128, t, h1f + (size_t)((ph - 1) & 1) * HU, wfc, bfc, out);
      }
      if (ph < NPH - 1) grid_barrier(bar, bar + 16);
    }
  }
}

}  // namespace

extern "C" void kernel_launch(void* const* d_in, const int* in_sizes, int n_in,
                              void* d_out, int out_size, void* d_ws, size_t ws_size,
                              hipStream_t stream) {
  const float* inputs = (const float*)d_in[0];
  const float* times  = (const float*)d_in[1];
  const float* k0     = (const float*)d_in[2];
  const float* rk0    = (const float*)d_in[3];
  const float* b0     = (const float*)d_in[4];
  const float* tau0   = (const float*)d_in[5];
  const float* s0     = (const float*)d_in[6];
  const float* k1     = (const float*)d_in[7];
  const float* rk1    = (const float*)d_in[8];
  const float* b1     = (const float*)d_in[9];
  const float* tau1   = (const float*)d_in[10];
  const float* s1     = (const float*)d_in[11];
  const float* wfc    = (const float*)d_in[12];
  const float* bfc    = (const float*)d_in[13];
  float* out = (float*)d_out;

  float* ws = (float*)d_ws;
  // layout (f32 slots): h0f[2*HU] | h1f[2*HU] | c0[HU] | c1[HU]
  //                     | h0hi[HU] | h0lo[HU] | h1hi[HU] | h1lo[HU] (ushort[2HU] each slot-pair)
  float* h0f = ws;                       // [2][HU]
  float* h1f = ws + 2 * HU;              // [2][HU]
  float* c0  = ws + 4 * HU;
  float* c1  = ws + 5 * HU;
  ushort* h0hi = (ushort*)(ws + 6 * HU); // [2][HU] bf16
  ushort* h0lo = (ushort*)(ws + 7 * HU);
  ushort* h1hi = (ushort*)(ws + 8 * HU);
  ushort* h1lo = (ushort*)(ws + 9 * HU);
  unsigned* bar = (unsigned*)(ws + 10 * HU);

  hipLaunchKernelGGL(init_kernel, dim3(2560), dim3(256), 0, stream, ws, bar);
  hipLaunchKernelGGL(plstm_kernel, dim3(GRID_BLOCKS), dim3(256), 0, stream,
                     inputs, times, k0, rk0, b0, tau0, s0,
                     k1, rk1, b1, tau1, s1, wfc, bfc, out,
                     h0f, h1f, c0, c1, h0hi, h0lo, h1hi, h1lo, bar);
}

// Round 3
// 37573.727 us; speedup vs baseline: 2.6464x; 1.1091x over previous
//
#include <hip/hip_runtime.h>
#include <math.h>

namespace {

typedef __attribute__((ext_vector_type(8))) short s8b;   // 8 x bf16 (bit pattern)
typedef __attribute__((ext_vector_type(4))) float f4;

constexpr int B_ = 128;
constexpr int T_ = 500;
constexpr int F_ = 64;
constexpr int U_ = 512;
constexpr int NCLS_ = 11;
constexpr int HU = B_ * U_;           // 65536
constexpr float R_ON_ = 0.05f;
constexpr float ALPHA_ = 0.001f;

constexpr int GRID_BLOCKS = 144;      // 64 cell0 + 64 cell1 + 16 classifier
constexpr int NPH = 502;              // phases 0..501

__device__ __forceinline__ ushort bf16_rne(float f) {
  union { float f; unsigned u; } v; v.f = f;
  unsigned r = (v.u + 0x7fffu + ((v.u >> 16) & 1u)) >> 16;
  return (ushort)r;
}
__device__ __forceinline__ float bf16_f(ushort h) {
  union { unsigned u; float f; } v; v.u = ((unsigned)h) << 16; return v.f;
}

// Sense-reversing grid barrier. RELAXED spin (coherent at agent scope, no
// cache invalidation per poll); ONE release at arrival (fetch_add) and ONE
// acquire fence per block per phase after wake. Periodic acquire poll as
// insurance against lowering surprises.
__device__ __forceinline__ void grid_barrier(unsigned* cnt, unsigned* gen) {
  __syncthreads();
  if (threadIdx.x == 0) {
    const unsigned g = __hip_atomic_load(gen, __ATOMIC_RELAXED, __HIP_MEMORY_SCOPE_AGENT);
    const unsigned a = __hip_atomic_fetch_add(cnt, 1u, __ATOMIC_RELEASE, __HIP_MEMORY_SCOPE_AGENT);
    if (a == (unsigned)(GRID_BLOCKS - 1)) {
      __hip_atomic_store(cnt, 0u, __ATOMIC_RELAXED, __HIP_MEMORY_SCOPE_AGENT);
      __hip_atomic_store(gen, g + 1u, __ATOMIC_RELEASE, __HIP_MEMORY_SCOPE_AGENT);
    } else {
      unsigned it = 0;
      for (;;) {
        const unsigned cur = ((++it & 63u) == 0u)
            ? __hip_atomic_load(gen, __ATOMIC_ACQUIRE, __HIP_MEMORY_SCOPE_AGENT)
            : __hip_atomic_load(gen, __ATOMIC_RELAXED, __HIP_MEMORY_SCOPE_AGENT);
        if (cur != g) break;
        __builtin_amdgcn_s_sleep(2);
      }
    }
    __builtin_amdgcn_fence(__ATOMIC_ACQUIRE, "agent");  // one inv per phase
  }
  __syncthreads();
}

// Persistent weight fragments (hi/lo bf16 split) from fp32 weights. One-time.
template <int NKS>
__device__ __forceinline__ void load_weights(
    s8b (&wh)[NKS], s8b (&wl)[NKS],
    const float* __restrict__ W1, int K1, const float* __restrict__ W2,
    int n, int kbase, int krow)
{
#pragma unroll
  for (int ks = 0; ks < NKS; ++ks) {
#pragma unroll
    for (int j = 0; j < 8; ++j) {
      const int kg = kbase + ks * 32 + krow + j;
      const float* src = (kg < K1) ? (W1 + (size_t)kg * 2048)
                                   : (W2 + (size_t)(kg - K1) * 2048);
      const float wv = src[n];
      const ushort hi = bf16_rne(wv);
      const ushort lo = bf16_rne(wv - bf16_f(hi));
      wh[ks][j] = (short)hi;
      wl[ks][j] = (short)lo;
    }
  }
}

// A-state in MFMA-fragment order: element (b,u) at
//   [((u>>5)*8 + (b>>4))*64 + ((b&15) | (((u>>3)&3)<<4))]*8 + (u&7)
// so a wave's (rt,kb) fragment load is one coalesced 1KB global_load_dwordx4.
template <int NKS, bool C0>
__device__ __forceinline__ void gemm_phase(
    const s8b (&wh)[NKS], const s8b (&wl)[NKS],
    int t, int ksl, int lane,
    const float* __restrict__ inputs,
    const ushort* __restrict__ Ahi, const ushort* __restrict__ Alo,
    int kbbase, f4 (&accs)[8])
{
  const int arow = lane & 15;
  const int krow = (lane >> 4) * 8;
#pragma unroll
  for (int rt = 0; rt < 8; ++rt) {
    f4 a0 = {0.f, 0.f, 0.f, 0.f};
    f4 a1 = {0.f, 0.f, 0.f, 0.f};
    f4 a2 = {0.f, 0.f, 0.f, 0.f};
#pragma unroll
    for (int ks = 0; ks < NKS; ++ks) {
      s8b ah, al;
      if (C0 && ksl == 0 && ks < 2) {
        const int row = rt * 16 + arow;
        const float* xp = inputs + ((size_t)row * T_ + t) * F_ + ks * 32 + krow;
        const float4 v0 = *(const float4*)xp;
        const float4 v1 = *(const float4*)(xp + 4);
        const float xv[8] = {v0.x, v0.y, v0.z, v0.w, v1.x, v1.y, v1.z, v1.w};
#pragma unroll
        for (int j = 0; j < 8; ++j) {
          const ushort hi = bf16_rne(xv[j]);
          ah[j] = (short)hi;
          al[j] = (short)bf16_rne(xv[j] - bf16_f(hi));
        }
      } else {
        const size_t off = (((size_t)(kbbase + ks) * 8 + rt) * 64 + lane) * 8;
        ah = *(const s8b*)(Ahi + off);
        al = *(const s8b*)(Alo + off);
      }
      a0 = __builtin_amdgcn_mfma_f32_16x16x32_bf16(ah, wh[ks], a0, 0, 0, 0);
      a1 = __builtin_amdgcn_mfma_f32_16x16x32_bf16(al, wh[ks], a1, 0, 0, 0);
      a2 = __builtin_amdgcn_mfma_f32_16x16x32_bf16(ah, wl[ks], a2, 0, 0, 0);
    }
    accs[rt] = a0 + a1 + a2;
  }
}

// K-reduce through LDS, then fused PhasedLSTM elementwise. c and h_old live
// in registers (thread b < 128 owns (b, u0..u0+7) for the whole sequence).
__device__ __forceinline__ void reduce_elem(
    f4 (&accs)[8], float* __restrict__ z_s,
    int tid, int lane, int ksl, int c_loc, int t, int u0,
    const float* __restrict__ bias, const float* __restrict__ tau,
    const float* __restrict__ shift, const float* __restrict__ timesT,
    float (&c8)[8], float (&h8)[8],
    float* __restrict__ hf_w,          // f32 row-major (cell1 only, for classifier)
    ushort* __restrict__ hhi_w, ushort* __restrict__ hlo_w)
{
  const int rbase = (lane >> 4) * 4;
  if (ksl == 0) {
#pragma unroll
    for (int rt = 0; rt < 8; ++rt)
      *(f4*)&z_s[c_loc * 132 + rt * 16 + rbase] = accs[rt];
  }
  __syncthreads();
  if (ksl == 1) {
#pragma unroll
    for (int rt = 0; rt < 8; ++rt) {
      f4* p = (f4*)&z_s[c_loc * 132 + rt * 16 + rbase];
      *p = *p + accs[rt];
    }
  }
  __syncthreads();

  if (tid < 128) {
    const int b = tid;
    const float tt = timesT[t * B_ + b];
    s8b vhi, vlo;
    f4 f32a, f32b;
#pragma unroll
    for (int uu = 0; uu < 8; ++uu) {
      const int u = u0 + uu;            // wave-uniform -> scalar loads below
      const float zi = z_s[(4 * uu + 0) * 132 + b] + bias[u];
      const float zf = z_s[(4 * uu + 1) * 132 + b] + bias[512 + u];
      const float zg = z_s[(4 * uu + 2) * 132 + b] + bias[1024 + u];
      const float zo = z_s[(4 * uu + 3) * 132 + b] + bias[1536 + u];

      const float ig = 1.f / (1.f + expf(-zi));
      const float fg = 1.f / (1.f + expf(-zf));
      const float gg = tanhf(zg);
      const float og = 1.f / (1.f + expf(-zo));

      const float c_old = c8[uu];
      const float c_t = fg * c_old + ig * gg;
      const float h_t = og * tanhf(c_t);

      const float tau_u = tau[u];
      float phi = fmodf(tt - shift[u], tau_u);
      if (phi < 0.f) phi += tau_u;
      phi /= tau_u;
      float kt;
      if (phi < 0.5f * R_ON_)      kt = phi * (2.0f / R_ON_);
      else if (phi < R_ON_)        kt = 2.0f - phi * (2.0f / R_ON_);
      else                         kt = ALPHA_ * phi;

      const float cn = kt * c_t + (1.0f - kt) * c_old;
      const float hn = kt * h_t + (1.0f - kt) * h8[uu];
      c8[uu] = cn;
      h8[uu] = hn;
      const ushort hi = bf16_rne(hn);
      vhi[uu] = (short)hi;
      vlo[uu] = (short)bf16_rne(hn - bf16_f(hi));
      if (uu < 4) f32a[uu] = hn; else f32b[uu - 4] = hn;
    }
    const size_t foff = ((((size_t)(u0 >> 5)) * 8 + (b >> 4)) * 64
                         + ((b & 15) | (((u0 >> 3) & 3) << 4))) * 8;
    *(s8b*)(hhi_w + foff) = vhi;
    *(s8b*)(hlo_w + foff) = vlo;
    if (hf_w) {
      *(f4*)(hf_w + (size_t)b * U_ + u0) = f32a;
      *(f4*)(hf_w + (size_t)b * U_ + u0 + 4) = f32b;
    }
  }
}

__device__ void classifier_step(int cb, int t,
    const float* __restrict__ h1s,
    const float* __restrict__ wfc, const float* __restrict__ bfc,
    float* __restrict__ out)
{
  const int tid = threadIdx.x;
  const int bl = tid >> 5;
  const int lane = tid & 31;
  const int b = cb * 8 + bl;
  const float* hrow = h1s + (size_t)b * U_;

  float acc[NCLS_];
#pragma unroll
  for (int c = 0; c < NCLS_; ++c) acc[c] = 0.f;
  for (int j = 0; j < U_ / 32; ++j) {
    const float h = hrow[lane + 32 * j];
    const float* w = wfc + (size_t)(lane + 32 * j) * NCLS_;
#pragma unroll
    for (int c = 0; c < NCLS_; ++c) acc[c] = fmaf(h, w[c], acc[c]);
  }
#pragma unroll
  for (int off = 16; off >= 1; off >>= 1) {
#pragma unroll
    for (int c = 0; c < NCLS_; ++c) acc[c] += __shfl_xor(acc[c], off, 64);
  }
  if (lane == 0) {
    float lg[NCLS_];
    float m = -1e30f;
#pragma unroll
    for (int c = 0; c < NCLS_; ++c) { lg[c] = acc[c] + bfc[c]; m = fmaxf(m, lg[c]); }
    float s = 0.f;
#pragma unroll
    for (int c = 0; c < NCLS_; ++c) { lg[c] = expf(lg[c] - m); s += lg[c]; }
    const float inv = 1.0f / s;
    float* op = out + ((size_t)b * T_ + t) * NCLS_;
#pragma unroll
    for (int c = 0; c < NCLS_; ++c) op[c] = lg[c] * inv;
  }
}

// ws layout (f32 slots):
//   h1f    [2*HU]  (f32 row-major, classifier input)      @ 0
//   h0hi   [2*HU ushort] = HU f32                         @ 2*HU
//   h0lo                                                  @ 3*HU
//   h1hi                                                  @ 4*HU
//   h1lo                                                  @ 5*HU
//   timesT [T*B f32]                                      @ 6*HU
//   bar                                                   @ 7*HU
__global__ void init_kernel(float* ws0, const float* times, float* timesT, unsigned* bar) {
  const int i = blockIdx.x * blockDim.x + threadIdx.x;
  if (i < 6 * HU) ws0[i] = 0.f;
  if (i < T_ * B_) {
    const int t = i >> 7, b = i & 127;
    timesT[i] = times[b * T_ + t];
  }
  if (i == 0) { bar[0] = 0u; bar[16] = 0u; }
}

// Phase ph: cell0 t=ph (blocks 0..63), cell1 t=ph-1 (blocks 64..127),
// classifier t=ph-2 (blocks 128..143). One grid barrier per phase.
__global__ __launch_bounds__(256, 1) void plstm_kernel(
    const float* __restrict__ inputs, const float* __restrict__ times,
    const float* __restrict__ k0, const float* __restrict__ rk0,
    const float* __restrict__ b0, const float* __restrict__ tau0, const float* __restrict__ s0,
    const float* __restrict__ k1, const float* __restrict__ rk1,
    const float* __restrict__ b1, const float* __restrict__ tau1, const float* __restrict__ s1,
    const float* __restrict__ wfc, const float* __restrict__ bfc,
    float* __restrict__ out,
    float* __restrict__ h1f,
    ushort* __restrict__ h0hi, ushort* __restrict__ h0lo,
    ushort* __restrict__ h1hi, ushort* __restrict__ h1lo,
    const float* __restrict__ timesT,
    unsigned* __restrict__ bar)
{
  __shared__ __align__(16) float z_s[32 * 132];
  const int bid = blockIdx.x;
  const int tid = threadIdx.x;
  const int w = tid >> 6;
  const int lane = tid & 63;
  const int ct = w & 1;
  const int ksl = w >> 1;
  const int c_loc = ct * 16 + (lane & 15);
  const int krow = (lane >> 4) * 8;

  if (bid < 64) {
    // ---- cell 0: K = 576 (64 x + 512 h0), K-slices of 288 ----
    const int u0 = bid * 8;
    const int n = (c_loc & 3) * 512 + u0 + (c_loc >> 2);
    s8b wh[9], wl[9];
    load_weights<9>(wh, wl, k0, 64, rk0, n, ksl * 288, krow);
    float c8[8], h8[8];
#pragma unroll
    for (int i = 0; i < 8; ++i) { c8[i] = 0.f; h8[i] = 0.f; }

    for (int ph = 0; ph < NPH; ++ph) {
      if (ph < T_) {
        const int t = ph;
        const ushort* Ahi = h0hi + (size_t)(ph & 1) * HU;
        const ushort* Alo = h0lo + (size_t)(ph & 1) * HU;
        f4 accs[8];
        gemm_phase<9, true>(wh, wl, t, ksl, lane, inputs, Ahi, Alo,
                            ksl ? 7 : -2, accs);
        const size_t wp = (size_t)((ph + 1) & 1) * HU;
        reduce_elem(accs, z_s, tid, lane, ksl, c_loc, t, u0,
                    b0, tau0, s0, timesT, c8, h8,
                    nullptr, h0hi + wp, h0lo + wp);
      }
      if (ph < NPH - 1) grid_barrier(bar, bar + 16);
    }
  } else if (bid < 128) {
    // ---- cell 1: K = 1024 (512 h0(t) + 512 h1(t-1)), K-slices of 512 ----
    const int u0 = (bid - 64) * 8;
    const int n = (c_loc & 3) * 512 + u0 + (c_loc >> 2);
    s8b wh[16], wl[16];
    load_weights<16>(wh, wl, k1, 512, rk1, n, ksl * 512, krow);
    float c8[8], h8[8];
#pragma unroll
    for (int i = 0; i < 8; ++i) { c8[i] = 0.f; h8[i] = 0.f; }

    for (int ph = 0; ph < NPH; ++ph) {
      const int t = ph - 1;
      if (t >= 0 && t < T_) {
        const size_t p_h0 = (size_t)(ph & 1) * HU;        // h0(t), written ph-1
        const size_t p_h1r = (size_t)((ph + 1) & 1) * HU; // h1(t-1)
        const ushort* Ahi = ksl ? (h1hi + p_h1r) : (h0hi + p_h0);
        const ushort* Alo = ksl ? (h1lo + p_h1r) : (h0lo + p_h0);
        f4 accs[8];
        gemm_phase<16, false>(wh, wl, t, ksl, lane, inputs, Ahi, Alo, 0, accs);
        const size_t wp = (size_t)(ph & 1) * HU;
        reduce_elem(accs, z_s, tid, lane, ksl, c_loc, t, u0,
                    b1, tau1, s1, timesT, c8, h8,
                    h1f + wp, h1hi + wp, h1lo + wp);
      }
      if (ph < NPH - 1) grid_barrier(bar, bar + 16);
    }
  } else {
    // ---- classifier ----
    for (int ph = 0; ph < NPH; ++ph) {
      const int t = ph - 2;
      if (t >= 0 && t < T_) {
        classifier_step(bid - 128, t, h1f + (size_t)((ph - 1) & 1) * HU, wfc, bfc, out);
      }
      if (ph < NPH - 1) grid_barrier(bar, bar + 16);
    }
  }
}

}  // namespace

extern "C" void kernel_launch(void* const* d_in, const int* in_sizes, int n_in,
                              void* d_out, int out_size, void* d_ws, size_t ws_size,
                              hipStream_t stream) {
  const float* inputs = (const float*)d_in[0];
  const float* times  = (const float*)d_in[1];
  const float* k0     = (const float*)d_in[2];
  const float* rk0    = (const float*)d_in[3];
  const float* b0     = (const float*)d_in[4];
  const float* tau0   = (const float*)d_in[5];
  const float* s0     = (const float*)d_in[6];
  const float* k1     = (const float*)d_in[7];
  const float* rk1    = (const float*)d_in[8];
  const float* b1     = (const float*)d_in[9];
  const float* tau1   = (const float*)d_in[10];
  const float* s1     = (const float*)d_in[11];
  const float* wfc    = (const float*)d_in[12];
  const float* bfc    = (const float*)d_in[13];
  float* out = (float*)d_out;

  float* ws = (float*)d_ws;
  float* h1f = ws;                        // [2][HU] f32
  ushort* h0hi = (ushort*)(ws + 2 * HU);  // [2][HU] bf16 frag
  ushort* h0lo = (ushort*)(ws + 3 * HU);
  ushort* h1hi = (ushort*)(ws + 4 * HU);
  ushort* h1lo = (ushort*)(ws + 5 * HU);
  float* timesT = ws + 6 * HU;            // [T][B]
  unsigned* bar = (unsigned*)(ws + 7 * HU);

  hipLaunchKernelGGL(init_kernel, dim3(1536), dim3(256), 0, stream,
                     ws, times, timesT, bar);
  hipLaunchKernelGGL(plstm_kernel, dim3(GRID_BLOCKS), dim3(256), 0, stream,
                     inputs, times, k0, rk0, b0, tau0, s0,
                     k1, rk1, b1, tau1, s1, wfc, bfc, out,
                     h1f, h0hi, h0lo, h1hi, h1lo, timesT, bar);
}

// Round 4
// 10375.477 us; speedup vs baseline: 9.5837x; 3.6214x over previous
//
#include <hip/hip_runtime.h>
#include <math.h>

namespace {

typedef __attribute__((ext_vector_type(8))) short s8b;   // 8 x bf16 (bit pattern)
typedef __attribute__((ext_vector_type(4))) float f4;
typedef unsigned long long u64;

constexpr int B_ = 128;
constexpr int T_ = 500;
constexpr int F_ = 64;
constexpr int U_ = 512;
constexpr int NCLS_ = 11;
constexpr int HU = B_ * U_;           // 65536
constexpr float R_ON_ = 0.05f;
constexpr float ALPHA_ = 0.001f;

constexpr int GRID_BLOCKS = 192;      // 64 cell0(+classifier) + 128 cell1
constexpr int NGRP = 24;              // barrier groups
constexpr int GSZ = 8;                // blocks per group (24*8 = 192)
constexpr int NPH = 502;              // phases 0..501

__device__ __forceinline__ ushort bf16_rne(float f) {
  union { float f; unsigned u; } v; v.f = f;
  unsigned r = (v.u + 0x7fffu + ((v.u >> 16) & 1u)) >> 16;
  return (ushort)r;
}
__device__ __forceinline__ float bf16_f(ushort h) {
  union { unsigned u; float f; } v; v.u = ((unsigned)h) << 16; return v.f;
}

__device__ __forceinline__ void st_u64(ushort* p, u64 v) {
  __hip_atomic_store((u64*)p, v, __ATOMIC_RELAXED, __HIP_MEMORY_SCOPE_AGENT);
}
__device__ __forceinline__ u64 ld_u64(const ushort* p) {
  return __hip_atomic_load((const u64*)p, __ATOMIC_RELAXED, __HIP_MEMORY_SCOPE_AGENT);
}
__device__ __forceinline__ u64 pack4(const ushort* h) {
  return (u64)h[0] | ((u64)h[1] << 16) | ((u64)h[2] << 32) | ((u64)h[3] << 48);
}

// LLC-coherent (L1/L2-bypass) 16B fragment load. ASYNC: result valid only
// after s_waitcnt vmcnt(0) + sched_barrier(0).
#define LDFRAG(dst, src) \
  asm volatile("global_load_dwordx4 %0, %1, off sc0 sc1" : "=&v"(dst) : "v"(src))

// fragment element offset (in ushorts) for state element (b, k)
__device__ __forceinline__ int foff(int b, int k) {
  return (((k >> 5) * 8 + (b >> 4)) * 64 + ((b & 15) | (((k >> 3) & 3) << 4))) * 8 + (k & 7);
}

// Fence-free hierarchical grid barrier over monotonic counters at LLC.
// Visibility contract: all cross-block data was stored write-through (agent
// atomics) and drained by the vmcnt(0) below; loads of that data bypass
// L1/L2 (sc0 sc1 / agent atomics), so no cache maintenance is needed.
__device__ __forceinline__ void phase_barrier(unsigned* grp, unsigned* root,
                                              unsigned* gen, int gid, unsigned ph) {
  asm volatile("s_waitcnt vmcnt(0)" ::: "memory");   // per-wave store drain
  __syncthreads();
  if (threadIdx.x == 0) {
    const unsigned old =
        __hip_atomic_fetch_add(&grp[gid * 32], 1u, __ATOMIC_RELAXED, __HIP_MEMORY_SCOPE_AGENT);
    if (old == ph * GSZ + (GSZ - 1)) {
      const unsigned r =
          __hip_atomic_fetch_add(root, 1u, __ATOMIC_RELAXED, __HIP_MEMORY_SCOPE_AGENT);
      if (r == ph * NGRP + (NGRP - 1)) {
        __hip_atomic_store(gen, ph + 1u, __ATOMIC_RELAXED, __HIP_MEMORY_SCOPE_AGENT);
      }
    }
    unsigned it = 0;
    for (;;) {
      const unsigned cur = ((++it & 255u) == 0u)
          ? __hip_atomic_load(gen, __ATOMIC_ACQUIRE, __HIP_MEMORY_SCOPE_AGENT)
          : __hip_atomic_load(gen, __ATOMIC_RELAXED, __HIP_MEMORY_SCOPE_AGENT);
      if (cur >= ph + 1u) break;
      __builtin_amdgcn_s_sleep(2);
    }
  }
  __syncthreads();
}

// Persistent weight fragments (hi/lo bf16 split) from fp32 weights. One-time.
template <int NKS>
__device__ __forceinline__ void load_weights(
    s8b (&wh)[NKS], s8b (&wl)[NKS],
    const float* __restrict__ W1, int K1, const float* __restrict__ W2,
    int n, int kbase, int krow)
{
#pragma unroll
  for (int ks = 0; ks < NKS; ++ks) {
#pragma unroll
    for (int j = 0; j < 8; ++j) {
      const int kg = kbase + ks * 32 + krow + j;
      const float* src = (kg < K1) ? (W1 + (size_t)kg * 2048)
                                   : (W2 + (size_t)(kg - K1) * 2048);
      const float wv = src[n];
      const ushort hi = bf16_rne(wv);
      const ushort lo = bf16_rne(wv - bf16_f(hi));
      wh[ks][j] = (short)hi;
      wl[ks][j] = (short)lo;
    }
  }
}

// One wave's GEMM slice: 16 cols x 128 rows x (NKS*32) K, 3-term bf16-split
// MFMA, per-rt staged sc0sc1 fragment loads, LDS atomic K-reduce into z_s.
template <int NKS>
__device__ __forceinline__ void gemm_cell(
    const s8b (&wh)[NKS], const s8b (&wl)[NKS],
    const ushort* __restrict__ Ahi, const ushort* __restrict__ Alo,
    int kbbase, bool withx, int t, const float* __restrict__ inputs,
    int lane, float* __restrict__ z_s, int zrow)
{
  const int rbase = (lane >> 4) * 4;
  const int krow = (lane >> 4) * 8;
#pragma unroll
  for (int rt = 0; rt < 8; ++rt) {
    s8b sh[NKS], sl[NKS];
#pragma unroll
    for (int ks = 0; ks < NKS; ++ks) {
      if (withx && ks < 2) continue;
      const int e = (((kbbase + ks) * 8 + rt) * 64 + lane) * 8;
      LDFRAG(sh[ks], Ahi + e);
      LDFRAG(sl[ks], Alo + e);
    }
    if (withx) {
      const int row = rt * 16 + (lane & 15);
#pragma unroll
      for (int ks = 0; ks < 2; ++ks) {
        const float* xp = inputs + ((size_t)row * T_ + t) * F_ + ks * 32 + krow;
        const float4 v0 = *(const float4*)xp;
        const float4 v1 = *(const float4*)(xp + 4);
        const float xv[8] = {v0.x, v0.y, v0.z, v0.w, v1.x, v1.y, v1.z, v1.w};
#pragma unroll
        for (int j = 0; j < 8; ++j) {
          const ushort hi = bf16_rne(xv[j]);
          sh[ks][j] = (short)hi;
          sl[ks][j] = (short)bf16_rne(xv[j] - bf16_f(hi));
        }
      }
    }
    asm volatile("s_waitcnt vmcnt(0)" ::: "memory");
    __builtin_amdgcn_sched_barrier(0);
    f4 a0 = {0.f, 0.f, 0.f, 0.f};
    f4 a1 = {0.f, 0.f, 0.f, 0.f};
    f4 a2 = {0.f, 0.f, 0.f, 0.f};
#pragma unroll
    for (int ks = 0; ks < NKS; ++ks) {
      a0 = __builtin_amdgcn_mfma_f32_16x16x32_bf16(sh[ks], wh[ks], a0, 0, 0, 0);
      a1 = __builtin_amdgcn_mfma_f32_16x16x32_bf16(sl[ks], wh[ks], a1, 0, 0, 0);
      a2 = __builtin_amdgcn_mfma_f32_16x16x32_bf16(sh[ks], wl[ks], a2, 0, 0, 0);
    }
    const f4 red = a0 + a1 + a2;
#pragma unroll
    for (int j = 0; j < 4; ++j)
      atomicAdd(&z_s[zrow * 133 + rt * 16 + rbase + j], red[j]);
  }
}

// Fused PhasedLSTM elementwise for NU units; c/h_old in registers; writes
// bf16 hi/lo state fragments write-through.
template <int NU>
__device__ __forceinline__ void elem_update(
    const float* __restrict__ z_s, int b, int t, int u0,
    const float* __restrict__ bias, const float* __restrict__ tau,
    const float* __restrict__ shift, const float* __restrict__ timesT,
    float (&c8)[NU], float (&h8)[NU],
    ushort* __restrict__ hhi_w, ushort* __restrict__ hlo_w)
{
  const float tt = timesT[t * B_ + b];
  ushort vh[NU], vl[NU];
#pragma unroll
  for (int uu = 0; uu < NU; ++uu) {
    const int u = u0 + uu;
    const float zi = z_s[(4 * uu + 0) * 133 + b] + bias[u];
    const float zf = z_s[(4 * uu + 1) * 133 + b] + bias[512 + u];
    const float zg = z_s[(4 * uu + 2) * 133 + b] + bias[1024 + u];
    const float zo = z_s[(4 * uu + 3) * 133 + b] + bias[1536 + u];

    const float ig = 1.f / (1.f + expf(-zi));
    const float fg = 1.f / (1.f + expf(-zf));
    const float gg = tanhf(zg);
    const float og = 1.f / (1.f + expf(-zo));

    const float c_old = c8[uu];
    const float c_t = fg * c_old + ig * gg;
    const float h_t = og * tanhf(c_t);

    const float tau_u = tau[u];
    float phi = fmodf(tt - shift[u], tau_u);
    if (phi < 0.f) phi += tau_u;
    phi /= tau_u;
    float kt;
    if (phi < 0.5f * R_ON_)      kt = phi * (2.0f / R_ON_);
    else if (phi < R_ON_)        kt = 2.0f - phi * (2.0f / R_ON_);
    else                         kt = ALPHA_ * phi;

    const float cn = kt * c_t + (1.0f - kt) * c_old;
    const float hn = kt * h_t + (1.0f - kt) * h8[uu];
    c8[uu] = cn;
    h8[uu] = hn;
    const ushort hi = bf16_rne(hn);
    vh[uu] = hi;
    vl[uu] = bf16_rne(hn - bf16_f(hi));
  }
  const int base = foff(b, u0);
#pragma unroll
  for (int q = 0; q < NU / 4; ++q) {
    st_u64(hhi_w + base + 4 * q, pack4(&vh[4 * q]));
    st_u64(hlo_w + base + 4 * q, pack4(&vl[4 * q]));
  }
}

// ws layout: h0hi[2HU] h0lo[2HU] h1hi[2HU] h1lo[2HU] (ushort) | timesT[T*B] f32 | bar
__global__ void init_kernel(unsigned* state_u32, const float* times, float* timesT,
                            unsigned* bar) {
  const int i = blockIdx.x * blockDim.x + threadIdx.x;
  if (i < 4 * HU) state_u32[i] = 0u;          // 8*HU ushorts
  if (i < T_ * B_) {
    const int t = i >> 7, b = i & 127;
    timesT[i] = times[b * T_ + t];
  }
  if (i < 4096) bar[i] = 0u;
}

// Phase ph: cell0 t=ph (blocks 0..63, 8 units each, + classifier t=ph-2,
// 2 batch rows each), cell1 t=ph-1 (blocks 64..191, 4 units each).
__global__ __launch_bounds__(256, 1) void plstm_kernel(
    const float* __restrict__ inputs,
    const float* __restrict__ k0, const float* __restrict__ rk0,
    const float* __restrict__ b0, const float* __restrict__ tau0, const float* __restrict__ s0,
    const float* __restrict__ k1, const float* __restrict__ rk1,
    const float* __restrict__ b1, const float* __restrict__ tau1, const float* __restrict__ s1,
    const float* __restrict__ wfc, const float* __restrict__ bfc,
    float* __restrict__ out,
    ushort* __restrict__ h0hi, ushort* __restrict__ h0lo,
    ushort* __restrict__ h1hi, ushort* __restrict__ h1lo,
    const float* __restrict__ timesT,
    unsigned* __restrict__ bar)
{
  __shared__ __align__(16) float z_s[32 * 133];
  __shared__ float cls_s[4][12];

  const int bid = blockIdx.x;
  const int tid = threadIdx.x;
  const int w = tid >> 6;
  const int lane = tid & 63;
  const int krow = (lane >> 4) * 8;
  const int gid = bid >> 3;
  unsigned* grp = bar;
  unsigned* root = bar + NGRP * 32;
  unsigned* gen = bar + NGRP * 32 + 32;

  if (bid < 64) {
    // ---- cell 0 (+ classifier): 8 units, 2 coltiles x 2 K-slices of 288 ----
    const int u0 = bid * 8;
    const int ct = w & 1;
    const int ksl = w >> 1;
    const int c_loc = ct * 16 + (lane & 15);
    const int n = (c_loc & 3) * 512 + u0 + (c_loc >> 2);
    s8b wh[9], wl[9];
    load_weights<9>(wh, wl, k0, 64, rk0, n, ksl * 288, krow);
    float c8[8], h8[8];
#pragma unroll
    for (int i = 0; i < 8; ++i) { c8[i] = 0.f; h8[i] = 0.f; }

    for (unsigned ph = 0; ph < NPH; ++ph) {
      const bool work = ph < T_;
      const bool clsw = ph >= 2;
      if (work) {
        for (int i = tid; i < 32 * 133; i += 256) z_s[i] = 0.f;
      }
      if (clsw) {  // classifier partial for t = ph-2 (all 4 waves)
        const int r = w >> 1;
        const int bcls = 2 * bid + r;
        const int idx = ((w & 1) << 6) | lane;   // 0..127
        const int u = idx * 4;
        const size_t pcl = (size_t)((ph + 1) & 1) * HU;
        const int e = foff(bcls, u);
        const u64 hu = ld_u64(h1hi + pcl + e);
        const u64 lu = ld_u64(h1lo + pcl + e);
        float acc[NCLS_];
#pragma unroll
        for (int c = 0; c < NCLS_; ++c) acc[c] = 0.f;
#pragma unroll
        for (int j = 0; j < 4; ++j) {
          const float h = bf16_f((ushort)(hu >> (16 * j))) + bf16_f((ushort)(lu >> (16 * j)));
          const float* wr = wfc + (size_t)(u + j) * NCLS_;
#pragma unroll
          for (int c = 0; c < NCLS_; ++c) acc[c] = fmaf(h, wr[c], acc[c]);
        }
#pragma unroll
        for (int off = 32; off >= 1; off >>= 1) {
#pragma unroll
          for (int c = 0; c < NCLS_; ++c) acc[c] += __shfl_xor(acc[c], off, 64);
        }
        if (lane == 0) {
#pragma unroll
          for (int c = 0; c < NCLS_; ++c) cls_s[w][c] = acc[c];
        }
      }
      __syncthreads();
      if (work) {
        const size_t rp = (size_t)(ph & 1) * HU;
        gemm_cell<9>(wh, wl, h0hi + rp, h0lo + rp, ksl ? 7 : -2,
                     ksl == 0, (int)ph, inputs, lane, z_s, c_loc);
      }
      __syncthreads();
      if (work && tid < 128) {
        const size_t wp = (size_t)((ph + 1) & 1) * HU;
        elem_update<8>(z_s, tid, (int)ph, u0, b0, tau0, s0, timesT,
                       c8, h8, h0hi + wp, h0lo + wp);
      }
      if (clsw && tid < 2) {
        const int t_cl = (int)ph - 2;
        const int bcls = 2 * bid + tid;
        float lg[NCLS_];
        float m = -1e30f;
#pragma unroll
        for (int c = 0; c < NCLS_; ++c) {
          lg[c] = cls_s[2 * tid][c] + cls_s[2 * tid + 1][c] + bfc[c];
          m = fmaxf(m, lg[c]);
        }
        float s = 0.f;
#pragma unroll
        for (int c = 0; c < NCLS_; ++c) { lg[c] = expf(lg[c] - m); s += lg[c]; }
        const float inv = 1.0f / s;
        float* op = out + ((size_t)bcls * T_ + t_cl) * NCLS_;
#pragma unroll
        for (int c = 0; c < NCLS_; ++c) op[c] = lg[c] * inv;
      }
      if (ph < NPH - 1) phase_barrier(grp, root, gen, gid, ph);
    }
  } else {
    // ---- cell 1: 4 units, 1 coltile x 4 K-slices of 256 ----
    const int cb = bid - 64;                 // 0..127
    const int u0 = cb * 4;
    const int c_loc = lane & 15;
    const int n = (c_loc & 3) * 512 + u0 + (c_loc >> 2);
    s8b wh[8], wl[8];
    load_weights<8>(wh, wl, k1, 512, rk1, n, w * 256, krow);
    float c8[4], h8[4];
#pragma unroll
    for (int i = 0; i < 4; ++i) { c8[i] = 0.f; h8[i] = 0.f; }

    for (unsigned ph = 0; ph < NPH; ++ph) {
      const int t = (int)ph - 1;
      const bool work = (t >= 0 && t < T_);
      if (work) {
        for (int i = tid; i < 16 * 133; i += 256) z_s[i] = 0.f;
      }
      __syncthreads();
      if (work) {
        const ushort* Ahi;
        const ushort* Alo;
        int kbb;
        if (w < 2) {               // k 0..511: h0(t), parity ph&1
          const size_t p = (size_t)(ph & 1) * HU;
          Ahi = h0hi + p; Alo = h0lo + p; kbb = w * 8;
        } else {                   // k 512..1023: h1(t-1), parity (ph+1)&1
          const size_t p = (size_t)((ph + 1) & 1) * HU;
          Ahi = h1hi + p; Alo = h1lo + p; kbb = (w - 2) * 8;
        }
        gemm_cell<8>(wh, wl, Ahi, Alo, kbb, false, 0, inputs, lane, z_s, c_loc);
      }
      __syncthreads();
      if (work && tid < 128) {
        const size_t wp = (size_t)(ph & 1) * HU;
        elem_update<4>(z_s, tid, t, u0, b1, tau1, s1, timesT,
                       c8, h8, h1hi + wp, h1lo + wp);
      }
      if (ph < NPH - 1) phase_barrier(grp, root, gen, gid, ph);
    }
  }
}

}  // namespace

extern "C" void kernel_launch(void* const* d_in, const int* in_sizes, int n_in,
                              void* d_out, int out_size, void* d_ws, size_t ws_size,
                              hipStream_t stream) {
  const float* inputs = (const float*)d_in[0];
  const float* times  = (const float*)d_in[1];
  const float* k0     = (const float*)d_in[2];
  const float* rk0    = (const float*)d_in[3];
  const float* b0     = (const float*)d_in[4];
  const float* tau0   = (const float*)d_in[5];
  const float* s0     = (const float*)d_in[6];
  const float* k1     = (const float*)d_in[7];
  const float* rk1    = (const float*)d_in[8];
  const float* b1     = (const float*)d_in[9];
  const float* tau1   = (const float*)d_in[10];
  const float* s1     = (const float*)d_in[11];
  const float* wfc    = (const float*)d_in[12];
  const float* bfc    = (const float*)d_in[13];
  float* out = (float*)d_out;

  ushort* h0hi = (ushort*)d_ws;            // [2][HU]
  ushort* h0lo = h0hi + 2 * HU;
  ushort* h1hi = h0lo + 2 * HU;
  ushort* h1lo = h1hi + 2 * HU;
  float* timesT = (float*)(h1lo + 2 * HU); // [T][B]
  unsigned* bar = (unsigned*)(timesT + T_ * B_);

  hipLaunchKernelGGL(init_kernel, dim3(1024), dim3(256), 0, stream,
                     (unsigned*)d_ws, times, timesT, bar);
  hipLaunchKernelGGL(plstm_kernel, dim3(GRID_BLOCKS), dim3(256), 0, stream,
                     inputs, k0, rk0, b0, tau0, s0,
                     k1, rk1, b1, tau1, s1, wfc, bfc, out,
                     h0hi, h0lo, h1hi, h1lo, timesT, bar);
}